// Round 23
// baseline (242.862 us; speedup 1.0000x reference)
//
#include <hip/hip_runtime.h>
#include <math.h>

#define NB 8
#define NN 10000
#define NE 160000
#define FD 64
#define BN (NB * NN)              // 80000
#define TOTE (NB * NE)            // 1280000
#define EPB 10000                 // edges per count chunk
#define BPG (NE / EPB)            // 16 chunks per graph
#define NPA (NB * BPG)            // 128 count blocks
#define FILLB 1000                // fill blocks: 125/graph, 5 edges/thread
#define LIN2B 625                 // register-blocked linear: 128 nodes/block
#define WS2 68                    // padded Wsh stride (272 B; 2-way read conflict = free)
#define AGGB 5000                 // agg blocks: 625/graph, 4 waves x 4 nodes = 16 nodes/block
#define SCB 80                    // scan blocks: 10 strips x 8 graphs
#define SPB 1000                  // nodes per strip

// ---------- 1: LDS histogram count + per-edge local rank (128 blocks) ----------
__global__ __launch_bounds__(256) void k_count_lds(const int* __restrict__ ei,
                                                   int* __restrict__ rank,
                                                   int* __restrict__ cnt) {
    __shared__ int hist[NN];  // 40 KB
    for (int i = threadIdx.x; i < NN; i += 256) hist[i] = 0;
    __syncthreads();
    int g = blockIdx.x >> 4;
    int j = blockIdx.x & 15;
    int base = g * NE + j * EPB;
    for (int i = threadIdx.x; i < EPB; i += 256) {
        int e = base + i;
        int r = ei[2 * e];
        rank[e] = atomicAdd(&hist[r], 1);
    }
    __syncthreads();
    int* cp = cnt + (size_t)blockIdx.x * NN;
    for (int i = threadIdx.x; i < NN; i += 256) cp[i] = hist[i];
}

// ---------- 2a: parallel scan phase A (80 blocks x 1024) ----------
__global__ __launch_bounds__(1024) void k_scanA(int* __restrict__ cnt,
                                                int* __restrict__ row_start,
                                                float* __restrict__ dinv,
                                                int* __restrict__ bsum) {
    __shared__ int wsums[16];
    const int b = blockIdx.x;
    const int g = b & 7;
    const int s = b >> 3;
    const int tid = threadIdx.x;
    const int lane = tid & 63;
    const int wv = tid >> 6;
    const int i = s * SPB + tid;                 // node index in graph (tid<1000 valid)
    int d = 0;
    int* cp = cnt + ((size_t)g * BPG) * NN + i;
    if (tid < SPB) {
        int run = 0;
#pragma unroll
        for (int j = 0; j < BPG; j++) {
            int v = cp[(size_t)j * NN];
            cp[(size_t)j * NN] = run;            // within-node chunk prefix
            run += v;
        }
        d = run;
    }
    int x = d;
#pragma unroll
    for (int off = 1; off < 64; off <<= 1) {
        int y = __shfl_up(x, off);
        if (lane >= off) x += y;
    }
    if (lane == 63) wsums[wv] = x;
    __syncthreads();
    if (wv == 0 && lane < 16) {
        int ss = wsums[lane];
#pragma unroll
        for (int off = 1; off < 16; off <<= 1) {
            int y = __shfl_up(ss, off, 16);
            if (lane >= off) ss += y;
        }
        wsums[lane] = ss;
    }
    __syncthreads();
    int excl = ((wv > 0) ? wsums[wv - 1] : 0) + (x - d);
    if (tid < SPB) {
        row_start[g * NN + i] = excl;            // TEMP: strip-local exclusive
        dinv[g * NN + i] = (d > 0) ? (1.0f / sqrtf((float)d)) : 0.0f;
    }
    if (tid == 0) bsum[b] = wsums[15];           // strip total
}

// ---------- register-blocked linear body ----------
template <bool DO_RELU>
__device__ __forceinline__ void lin2_body(int lb,
                                          const float* __restrict__ hin,
                                          const float* __restrict__ W,
                                          const float* __restrict__ bias,
                                          const float* __restrict__ dinv,
                                          float* __restrict__ tout) {
    __shared__ __align__(16) float Wsh[FD * WS2];   // 17.4 KB
    __shared__ float bsh[FD];
    for (int idx = threadIdx.x; idx < FD * FD; idx += 256) {
        int j = idx >> 6, k = idx & 63;
        Wsh[k * WS2 + j] = W[idx];                  // Wsh[k][j] = W[j][k]
    }
    if (threadIdx.x < FD) bsh[threadIdx.x] = bias[threadIdx.x];
    __syncthreads();

    const int lane = (int)threadIdx.x & 63;
    const int wv   = (int)threadIdx.x >> 6;
    const int jq   = lane & 7;
    const int nq   = lane >> 3;
    const int n0   = lb * 128 + wv * 32 + nq * 4;

    float4 bv0 = *(const float4*)&bsh[jq * 8];
    float4 bv1 = *(const float4*)&bsh[jq * 8 + 4];
    float a[4][8];
#pragma unroll
    for (int m = 0; m < 4; m++) {
        a[m][0] = bv0.x; a[m][1] = bv0.y; a[m][2] = bv0.z; a[m][3] = bv0.w;
        a[m][4] = bv1.x; a[m][5] = bv1.y; a[m][6] = bv1.z; a[m][7] = bv1.w;
    }

    const float*  wl = &Wsh[jq * 8];
    const float4* h0 = (const float4*)(hin + (size_t)(n0 + 0) * FD);
    const float4* h1 = (const float4*)(hin + (size_t)(n0 + 1) * FD);
    const float4* h2 = (const float4*)(hin + (size_t)(n0 + 2) * FD);
    const float4* h3 = (const float4*)(hin + (size_t)(n0 + 3) * FD);

    for (int kq = 0; kq < 16; kq++) {
        float4 hm[4];
        hm[0] = h0[kq]; hm[1] = h1[kq]; hm[2] = h2[kq]; hm[3] = h3[kq];
        if (DO_RELU) {
#pragma unroll
            for (int m = 0; m < 4; m++) {
                hm[m].x = fmaxf(hm[m].x, 0.f); hm[m].y = fmaxf(hm[m].y, 0.f);
                hm[m].z = fmaxf(hm[m].z, 0.f); hm[m].w = fmaxf(hm[m].w, 0.f);
            }
        }
        const float* wk = wl + kq * 4 * WS2;
#pragma unroll
        for (int kk = 0; kk < 4; kk++) {
            float4 w0 = *(const float4*)(wk + kk * WS2);
            float4 w1 = *(const float4*)(wk + kk * WS2 + 4);
#pragma unroll
            for (int m = 0; m < 4; m++) {
                float hk = (kk == 0) ? hm[m].x : (kk == 1) ? hm[m].y
                         : (kk == 2) ? hm[m].z : hm[m].w;
                a[m][0] += hk * w0.x; a[m][1] += hk * w0.y;
                a[m][2] += hk * w0.z; a[m][3] += hk * w0.w;
                a[m][4] += hk * w1.x; a[m][5] += hk * w1.y;
                a[m][6] += hk * w1.z; a[m][7] += hk * w1.w;
            }
        }
    }
#pragma unroll
    for (int m = 0; m < 4; m++) {
        float dn = dinv[n0 + m];
        float* orow = tout + (size_t)(n0 + m) * FD + jq * 8;
        *(float4*)orow =
            make_float4(dn * a[m][0], dn * a[m][1], dn * a[m][2], dn * a[m][3]);
        *(float4*)(orow + 4) =
            make_float4(dn * a[m][4], dn * a[m][5], dn * a[m][6], dn * a[m][7]);
    }
}

// ---------- 2b: scan phase C (blocks 0..79) + linear1 (blocks 80..704) ----------
__global__ __launch_bounds__(256) void k_scanC_lin(const int* __restrict__ bsum,
                                                   int* __restrict__ cnt,
                                                   int* __restrict__ row_start,
                                                   const float* __restrict__ x,
                                                   const float* __restrict__ W1,
                                                   const float* __restrict__ b1,
                                                   const float* __restrict__ dinv,
                                                   float* __restrict__ t1) {
    if (blockIdx.x < SCB) {
        const int b = blockIdx.x;
        const int g = b & 7;
        const int s = b >> 3;
        int carry = 0;
        for (int s2 = 0; s2 < s; s2++) carry += bsum[s2 * 8 + g];
        const int base = g * NE + carry;
        for (int i = s * SPB + (int)threadIdx.x; i < s * SPB + SPB; i += 256) {
            int abs0 = base + row_start[g * NN + i];
            row_start[g * NN + i] = abs0;
            int* cp = cnt + ((size_t)g * BPG) * NN + i;
#pragma unroll
            for (int j = 0; j < BPG; j++) cp[(size_t)j * NN] += abs0;  // -> start2
        }
        if (b == 0 && threadIdx.x == 0) row_start[BN] = TOTE;
    } else {
        lin2_body<false>((int)blockIdx.x - SCB, x, W1, b1, dinv, t1);
    }
}

// ---------- 3: fill CSR col-only (1000 blocks, 5 edges/thread) ----------
__global__ __launch_bounds__(256) void k_fill(const int* __restrict__ ei,
                                              const int* __restrict__ rank,
                                              const int* __restrict__ start2,
                                              int* __restrict__ edge_col) {
    int g = blockIdx.x & 7;
    int j = blockIdx.x >> 3;                 // 0..124
    int base = j * 1280 + (int)threadIdx.x;
    int2 rc[5];
    int rk[5];
    int idxs[5];
#pragma unroll
    for (int u = 0; u < 5; u++) {
        int idx = base + u * 256;
        idxs[u] = idx;
        int e = g * NE + idx;
        rc[u] = ((const int2*)ei)[e];
        rk[u] = rank[g * NE + idx];
    }
    int pos[5];
#pragma unroll
    for (int u = 0; u < 5; u++) {
        int jj = idxs[u] / EPB;
        pos[u] = start2[((size_t)(g * BPG + jj)) * NN + rc[u].x] + rk[u];
    }
#pragma unroll
    for (int u = 0; u < 5; u++)
        edge_col[pos[u]] = g * NN + rc[u].y;
}

// ---------- linear (layers 2,3) ----------
__global__ __launch_bounds__(256) void k_linear(const float* __restrict__ hin,
                                                const float* __restrict__ W,
                                                const float* __restrict__ bias,
                                                const float* __restrict__ dinv,
                                                float* __restrict__ tout) {
    lin2_body<true>((int)blockIdx.x, hin, W, bias, dinv, tout);
}

// ---------- aggregate: 4 nodes/wave, 2-deep gather pipeline ----------
// 5000 blocks, ZERO LDS, lean registers. FUSION FAMILY CLOSED (r6: grid cut +
// LDS -> 71.7us; r15: VGPR heuristic caps at 32, pipeline spilled -> 87.8us;
// r19: __launch_bounds__(256,4) does NOT raise allocator's choice, still
// VGPR=32 -> 86.6us). Keep agg lean; keep linear separate.
__global__ __launch_bounds__(256) void k_agg(const float* __restrict__ t,
                                             const int* __restrict__ row_start,
                                             const int* __restrict__ edge_col,
                                             const float* __restrict__ dinv,
                                             float* __restrict__ out) {
    int g = blockIdx.x & 7;
    int i = blockIdx.x >> 3;                          // 0..624
    int lane = threadIdx.x & 63;
    int eg = lane >> 4;
    int fl = lane & 15;
    int node0 = __builtin_amdgcn_readfirstlane(
        g * NN + i * 16 + ((int)threadIdx.x >> 6) * 4);

    int p[5];
#pragma unroll
    for (int u = 0; u < 5; u++) p[u] = row_start[node0 + u];
    float dr[4];
#pragma unroll
    for (int u = 0; u < 4; u++) dr[u] = dinv[node0 + u];

    int cols[4];
    int cnt[4];
#pragma unroll
    for (int u = 0; u < 4; u++) {
        int pl = p[u] + lane;
        cols[u] = (pl < p[u + 1]) ? edge_col[pl] : 0;
        int c = p[u + 1] - p[u];
        cnt[u] = (c > 64) ? 64 : c;
    }
    int kmax = 0;
#pragma unroll
    for (int u = 0; u < 4; u++) {
        int km = (cnt[u] + 3) >> 2;
        kmax = (km > kmax) ? km : kmax;
    }

    float4 acc[4];
#pragma unroll
    for (int u = 0; u < 4; u++) acc[u] = make_float4(0.f, 0.f, 0.f, 0.f);

    // prologue: issue k=0's gathers
    float4 tv[4];
#pragma unroll
    for (int u = 0; u < 4; u++) {
        int c = __shfl(cols[u], eg);
        tv[u] = make_float4(0.f, 0.f, 0.f, 0.f);
        if (eg < cnt[u]) tv[u] = ((const float4*)(t + (size_t)c * FD))[fl];
    }

    for (int k = 0; k < kmax; k++) {
        int s1 = (k + 1) * 4 + eg;                   // next slot
        float4 nv[4];
#pragma unroll
        for (int u = 0; u < 4; u++) {
            int c = __shfl(cols[u], s1 & 63);        // wrap-safe; masked off if OOR
            nv[u] = make_float4(0.f, 0.f, 0.f, 0.f);
            if (s1 < cnt[u]) nv[u] = ((const float4*)(t + (size_t)c * FD))[fl];
        }
#pragma unroll
        for (int u = 0; u < 4; u++) {
            acc[u].x += tv[u].x; acc[u].y += tv[u].y;
            acc[u].z += tv[u].z; acc[u].w += tv[u].w;
            tv[u] = nv[u];
        }
    }
    // rare overflow (deg > 64): per-edge cleanup
#pragma unroll
    for (int u = 0; u < 4; u++) {
        for (int q = p[u] + 64 + eg; q < p[u + 1]; q += 4) {
            int c = edge_col[q];
            float4 tvv = ((const float4*)(t + (size_t)c * FD))[fl];
            acc[u].x += tvv.x; acc[u].y += tvv.y;
            acc[u].z += tvv.z; acc[u].w += tvv.w;
        }
    }
#pragma unroll
    for (int u = 0; u < 4; u++) {
        acc[u].x += __shfl_down(acc[u].x, 32); acc[u].y += __shfl_down(acc[u].y, 32);
        acc[u].z += __shfl_down(acc[u].z, 32); acc[u].w += __shfl_down(acc[u].w, 32);
        acc[u].x += __shfl_down(acc[u].x, 16); acc[u].y += __shfl_down(acc[u].y, 16);
        acc[u].z += __shfl_down(acc[u].z, 16); acc[u].w += __shfl_down(acc[u].w, 16);
    }
    if (lane < 16) {
#pragma unroll
        for (int u = 0; u < 4; u++) {
            float4* op = (float4*)(out + (size_t)(node0 + u) * FD);
            op[fl] = make_float4(dr[u] * acc[u].x, dr[u] * acc[u].y,
                                 dr[u] * acc[u].z, dr[u] * acc[u].w);
        }
    }
}

extern "C" void kernel_launch(void* const* d_in, const int* in_sizes, int n_in,
                              void* d_out, int out_size, void* d_ws, size_t ws_size,
                              hipStream_t stream) {
    const float* x  = (const float*)d_in[0];
    const int*   ei = (const int*)d_in[1];
    const float* W1 = (const float*)d_in[2];
    const float* b1 = (const float*)d_in[3];
    const float* W2 = (const float*)d_in[4];
    const float* b2 = (const float*)d_in[5];
    const float* W3 = (const float*)d_in[6];
    const float* b3 = (const float*)d_in[7];
    float* out = (float*)d_out;

    char* ws = (char*)d_ws;
    size_t off = 0;
    float* A        = (float*)(ws + off); off += (size_t)BN * FD * 4;     // 20.48 MB
    float* Bb       = (float*)(ws + off); off += (size_t)BN * FD * 4;     // 20.48 MB
    int*   edge_col = (int*)(ws + off);   off += (size_t)TOTE * 4;        // 5.12 MB
    int*   row_start= (int*)(ws + off);   off += (size_t)(BN + 1) * 4;
    float* dinv     = (float*)(ws + off); off += (size_t)BN * 4;
    int*   bsum     = (int*)(ws + off);   off += (size_t)SCB * 4;
    // rank + cnt/start2 alias Bb (dead after k_fill; Bb first rewritten by agg1)
    int*   rank     = (int*)Bb;
    int*   cnt      = (int*)Bb + (size_t)TOTE;

    k_count_lds<<<NPA, 256, 0, stream>>>(ei, rank, cnt);
    k_scanA<<<SCB, 1024, 0, stream>>>(cnt, row_start, dinv, bsum);
    k_scanC_lin<<<SCB + LIN2B, 256, 0, stream>>>(bsum, cnt, row_start,
                                                 x, W1, b1, dinv, A);     // A = t1'
    k_fill<<<FILLB, 256, 0, stream>>>(ei, rank, cnt, edge_col);
    k_agg<<<AGGB, 256, 0, stream>>>(A, row_start, edge_col, dinv, Bb);   // B = h1
    k_linear<<<LIN2B, 256, 0, stream>>>(Bb, W2, b2, dinv, A);            // A = t2'
    k_agg<<<AGGB, 256, 0, stream>>>(A, row_start, edge_col, dinv, Bb);   // B = h2
    k_linear<<<LIN2B, 256, 0, stream>>>(Bb, W3, b3, dinv, A);            // A = t3'
    k_agg<<<AGGB, 256, 0, stream>>>(A, row_start, edge_col, dinv, out);  // out = h3
}

// Round 24
// 232.971 us; speedup vs baseline: 1.0425x; 1.0425x over previous
//
#include <hip/hip_runtime.h>
#include <math.h>

#define NB 8
#define NN 10000
#define NE 160000
#define FD 64
#define BN (NB * NN)              // 80000
#define TOTE (NB * NE)            // 1280000
#define EPB 10000                 // edges per count chunk
#define BPG (NE / EPB)            // 16 chunks per graph
#define NPA (NB * BPG)            // 128 count blocks
#define FILLB 1000                // fill blocks: 125/graph, 5 edges/thread
#define LIN2B 625                 // register-blocked linear: 128 nodes/block
#define WS2 68                    // padded Wsh stride (272 B; 2-way read conflict = free)
#define AGGB 5000                 // agg blocks: 625/graph, 4 waves x 4 nodes = 16 nodes/block
#define SCB 80                    // scan blocks: 10 strips x 8 graphs
#define SPB 1000                  // nodes per strip

// ---------- 1: LDS histogram count + per-edge local rank (128 blocks) ----------
__global__ __launch_bounds__(256) void k_count_lds(const int* __restrict__ ei,
                                                   int* __restrict__ rank,
                                                   int* __restrict__ cnt) {
    __shared__ int hist[NN];  // 40 KB
    for (int i = threadIdx.x; i < NN; i += 256) hist[i] = 0;
    __syncthreads();
    int g = blockIdx.x >> 4;
    int j = blockIdx.x & 15;
    int base = g * NE + j * EPB;
    for (int i = threadIdx.x; i < EPB; i += 256) {
        int e = base + i;
        int r = ei[2 * e];
        rank[e] = atomicAdd(&hist[r], 1);
    }
    __syncthreads();
    int* cp = cnt + (size_t)blockIdx.x * NN;
    for (int i = threadIdx.x; i < NN; i += 256) cp[i] = hist[i];
}

// ---------- 2a: parallel scan phase A (80 blocks x 1024) ----------
__global__ __launch_bounds__(1024) void k_scanA(int* __restrict__ cnt,
                                                int* __restrict__ row_start,
                                                float* __restrict__ dinv,
                                                int* __restrict__ bsum) {
    __shared__ int wsums[16];
    const int b = blockIdx.x;
    const int g = b & 7;
    const int s = b >> 3;
    const int tid = threadIdx.x;
    const int lane = tid & 63;
    const int wv = tid >> 6;
    const int i = s * SPB + tid;                 // node index in graph (tid<1000 valid)
    int d = 0;
    int* cp = cnt + ((size_t)g * BPG) * NN + i;
    if (tid < SPB) {
        int run = 0;
#pragma unroll
        for (int j = 0; j < BPG; j++) {
            int v = cp[(size_t)j * NN];
            cp[(size_t)j * NN] = run;            // within-node chunk prefix
            run += v;
        }
        d = run;
    }
    int x = d;
#pragma unroll
    for (int off = 1; off < 64; off <<= 1) {
        int y = __shfl_up(x, off);
        if (lane >= off) x += y;
    }
    if (lane == 63) wsums[wv] = x;
    __syncthreads();
    if (wv == 0 && lane < 16) {
        int ss = wsums[lane];
#pragma unroll
        for (int off = 1; off < 16; off <<= 1) {
            int y = __shfl_up(ss, off, 16);
            if (lane >= off) ss += y;
        }
        wsums[lane] = ss;
    }
    __syncthreads();
    int excl = ((wv > 0) ? wsums[wv - 1] : 0) + (x - d);
    if (tid < SPB) {
        row_start[g * NN + i] = excl;            // TEMP: strip-local exclusive
        dinv[g * NN + i] = (d > 0) ? (1.0f / sqrtf((float)d)) : 0.0f;
    }
    if (tid == 0) bsum[b] = wsums[15];           // strip total
}

// ---------- register-blocked linear body ----------
template <bool DO_RELU>
__device__ __forceinline__ void lin2_body(int lb,
                                          const float* __restrict__ hin,
                                          const float* __restrict__ W,
                                          const float* __restrict__ bias,
                                          const float* __restrict__ dinv,
                                          float* __restrict__ tout) {
    __shared__ __align__(16) float Wsh[FD * WS2];   // 17.4 KB
    __shared__ float bsh[FD];
    for (int idx = threadIdx.x; idx < FD * FD; idx += 256) {
        int j = idx >> 6, k = idx & 63;
        Wsh[k * WS2 + j] = W[idx];                  // Wsh[k][j] = W[j][k]
    }
    if (threadIdx.x < FD) bsh[threadIdx.x] = bias[threadIdx.x];
    __syncthreads();

    const int lane = (int)threadIdx.x & 63;
    const int wv   = (int)threadIdx.x >> 6;
    const int jq   = lane & 7;
    const int nq   = lane >> 3;
    const int n0   = lb * 128 + wv * 32 + nq * 4;

    float4 bv0 = *(const float4*)&bsh[jq * 8];
    float4 bv1 = *(const float4*)&bsh[jq * 8 + 4];
    float a[4][8];
#pragma unroll
    for (int m = 0; m < 4; m++) {
        a[m][0] = bv0.x; a[m][1] = bv0.y; a[m][2] = bv0.z; a[m][3] = bv0.w;
        a[m][4] = bv1.x; a[m][5] = bv1.y; a[m][6] = bv1.z; a[m][7] = bv1.w;
    }

    const float*  wl = &Wsh[jq * 8];
    const float4* h0 = (const float4*)(hin + (size_t)(n0 + 0) * FD);
    const float4* h1 = (const float4*)(hin + (size_t)(n0 + 1) * FD);
    const float4* h2 = (const float4*)(hin + (size_t)(n0 + 2) * FD);
    const float4* h3 = (const float4*)(hin + (size_t)(n0 + 3) * FD);

    for (int kq = 0; kq < 16; kq++) {
        float4 hm[4];
        hm[0] = h0[kq]; hm[1] = h1[kq]; hm[2] = h2[kq]; hm[3] = h3[kq];
        if (DO_RELU) {
#pragma unroll
            for (int m = 0; m < 4; m++) {
                hm[m].x = fmaxf(hm[m].x, 0.f); hm[m].y = fmaxf(hm[m].y, 0.f);
                hm[m].z = fmaxf(hm[m].z, 0.f); hm[m].w = fmaxf(hm[m].w, 0.f);
            }
        }
        const float* wk = wl + kq * 4 * WS2;
#pragma unroll
        for (int kk = 0; kk < 4; kk++) {
            float4 w0 = *(const float4*)(wk + kk * WS2);
            float4 w1 = *(const float4*)(wk + kk * WS2 + 4);
#pragma unroll
            for (int m = 0; m < 4; m++) {
                float hk = (kk == 0) ? hm[m].x : (kk == 1) ? hm[m].y
                         : (kk == 2) ? hm[m].z : hm[m].w;
                a[m][0] += hk * w0.x; a[m][1] += hk * w0.y;
                a[m][2] += hk * w0.z; a[m][3] += hk * w0.w;
                a[m][4] += hk * w1.x; a[m][5] += hk * w1.y;
                a[m][6] += hk * w1.z; a[m][7] += hk * w1.w;
            }
        }
    }
#pragma unroll
    for (int m = 0; m < 4; m++) {
        float dn = dinv[n0 + m];
        float* orow = tout + (size_t)(n0 + m) * FD + jq * 8;
        *(float4*)orow =
            make_float4(dn * a[m][0], dn * a[m][1], dn * a[m][2], dn * a[m][3]);
        *(float4*)(orow + 4) =
            make_float4(dn * a[m][4], dn * a[m][5], dn * a[m][6], dn * a[m][7]);
    }
}

// ---------- 2b: scan phase C (blocks 0..79) + linear1 (blocks 80..704) ----------
__global__ __launch_bounds__(256) void k_scanC_lin(const int* __restrict__ bsum,
                                                   int* __restrict__ cnt,
                                                   int* __restrict__ row_start,
                                                   const float* __restrict__ x,
                                                   const float* __restrict__ W1,
                                                   const float* __restrict__ b1,
                                                   const float* __restrict__ dinv,
                                                   float* __restrict__ t1) {
    if (blockIdx.x < SCB) {
        const int b = blockIdx.x;
        const int g = b & 7;
        const int s = b >> 3;
        int carry = 0;
        for (int s2 = 0; s2 < s; s2++) carry += bsum[s2 * 8 + g];
        const int base = g * NE + carry;
        for (int i = s * SPB + (int)threadIdx.x; i < s * SPB + SPB; i += 256) {
            int abs0 = base + row_start[g * NN + i];
            row_start[g * NN + i] = abs0;
            int* cp = cnt + ((size_t)g * BPG) * NN + i;
#pragma unroll
            for (int j = 0; j < BPG; j++) cp[(size_t)j * NN] += abs0;  // -> start2
        }
        if (b == 0 && threadIdx.x == 0) row_start[BN] = TOTE;
    } else {
        lin2_body<false>((int)blockIdx.x - SCB, x, W1, b1, dinv, t1);
    }
}

// ---------- 3: fill CSR col-only (1000 blocks, 5 edges/thread) ----------
__global__ __launch_bounds__(256) void k_fill(const int* __restrict__ ei,
                                              const int* __restrict__ rank,
                                              const int* __restrict__ start2,
                                              int* __restrict__ edge_col) {
    int g = blockIdx.x & 7;
    int j = blockIdx.x >> 3;                 // 0..124
    int base = j * 1280 + (int)threadIdx.x;
    int2 rc[5];
    int rk[5];
    int idxs[5];
#pragma unroll
    for (int u = 0; u < 5; u++) {
        int idx = base + u * 256;
        idxs[u] = idx;
        int e = g * NE + idx;
        rc[u] = ((const int2*)ei)[e];
        rk[u] = rank[g * NE + idx];
    }
    int pos[5];
#pragma unroll
    for (int u = 0; u < 5; u++) {
        int jj = idxs[u] / EPB;
        pos[u] = start2[((size_t)(g * BPG + jj)) * NN + rc[u].x] + rk[u];
    }
#pragma unroll
    for (int u = 0; u < 5; u++)
        edge_col[pos[u]] = g * NN + rc[u].y;
}

// ---------- linear (layers 2,3) ----------
__global__ __launch_bounds__(256) void k_linear(const float* __restrict__ hin,
                                                const float* __restrict__ W,
                                                const float* __restrict__ bias,
                                                const float* __restrict__ dinv,
                                                float* __restrict__ tout) {
    lin2_body<true>((int)blockIdx.x, hin, W, bias, dinv, tout);
}

// ---------- aggregate: 4 nodes/wave, 2-deep gather pipeline ----------
// 5000 blocks, ZERO LDS, lean registers. FUSION FAMILY CLOSED (r6: grid cut +
// LDS -> 71.7us; r15: VGPR heuristic caps at 32, pipeline spilled -> 87.8us;
// r19: __launch_bounds__(256,4) does NOT raise allocator's choice, still
// VGPR=32 -> 86.6us). Keep agg lean; keep linear separate.
__global__ __launch_bounds__(256) void k_agg(const float* __restrict__ t,
                                             const int* __restrict__ row_start,
                                             const int* __restrict__ edge_col,
                                             const float* __restrict__ dinv,
                                             float* __restrict__ out) {
    int g = blockIdx.x & 7;
    int i = blockIdx.x >> 3;                          // 0..624
    int lane = threadIdx.x & 63;
    int eg = lane >> 4;
    int fl = lane & 15;
    int node0 = __builtin_amdgcn_readfirstlane(
        g * NN + i * 16 + ((int)threadIdx.x >> 6) * 4);

    int p[5];
#pragma unroll
    for (int u = 0; u < 5; u++) p[u] = row_start[node0 + u];
    float dr[4];
#pragma unroll
    for (int u = 0; u < 4; u++) dr[u] = dinv[node0 + u];

    int cols[4];
    int cnt[4];
#pragma unroll
    for (int u = 0; u < 4; u++) {
        int pl = p[u] + lane;
        cols[u] = (pl < p[u + 1]) ? edge_col[pl] : 0;
        int c = p[u + 1] - p[u];
        cnt[u] = (c > 64) ? 64 : c;
    }
    int kmax = 0;
#pragma unroll
    for (int u = 0; u < 4; u++) {
        int km = (cnt[u] + 3) >> 2;
        kmax = (km > kmax) ? km : kmax;
    }

    float4 acc[4];
#pragma unroll
    for (int u = 0; u < 4; u++) acc[u] = make_float4(0.f, 0.f, 0.f, 0.f);

    // prologue: issue k=0's gathers
    float4 tv[4];
#pragma unroll
    for (int u = 0; u < 4; u++) {
        int c = __shfl(cols[u], eg);
        tv[u] = make_float4(0.f, 0.f, 0.f, 0.f);
        if (eg < cnt[u]) tv[u] = ((const float4*)(t + (size_t)c * FD))[fl];
    }

    for (int k = 0; k < kmax; k++) {
        int s1 = (k + 1) * 4 + eg;                   // next slot
        float4 nv[4];
#pragma unroll
        for (int u = 0; u < 4; u++) {
            int c = __shfl(cols[u], s1 & 63);        // wrap-safe; masked off if OOR
            nv[u] = make_float4(0.f, 0.f, 0.f, 0.f);
            if (s1 < cnt[u]) nv[u] = ((const float4*)(t + (size_t)c * FD))[fl];
        }
#pragma unroll
        for (int u = 0; u < 4; u++) {
            acc[u].x += tv[u].x; acc[u].y += tv[u].y;
            acc[u].z += tv[u].z; acc[u].w += tv[u].w;
            tv[u] = nv[u];
        }
    }
    // rare overflow (deg > 64): per-edge cleanup
#pragma unroll
    for (int u = 0; u < 4; u++) {
        for (int q = p[u] + 64 + eg; q < p[u + 1]; q += 4) {
            int c = edge_col[q];
            float4 tvv = ((const float4*)(t + (size_t)c * FD))[fl];
            acc[u].x += tvv.x; acc[u].y += tvv.y;
            acc[u].z += tvv.z; acc[u].w += tvv.w;
        }
    }
#pragma unroll
    for (int u = 0; u < 4; u++) {
        acc[u].x += __shfl_down(acc[u].x, 32); acc[u].y += __shfl_down(acc[u].y, 32);
        acc[u].z += __shfl_down(acc[u].z, 32); acc[u].w += __shfl_down(acc[u].w, 32);
        acc[u].x += __shfl_down(acc[u].x, 16); acc[u].y += __shfl_down(acc[u].y, 16);
        acc[u].z += __shfl_down(acc[u].z, 16); acc[u].w += __shfl_down(acc[u].w, 16);
    }
    if (lane < 16) {
#pragma unroll
        for (int u = 0; u < 4; u++) {
            float4* op = (float4*)(out + (size_t)(node0 + u) * FD);
            op[fl] = make_float4(dr[u] * acc[u].x, dr[u] * acc[u].y,
                                 dr[u] * acc[u].z, dr[u] * acc[u].w);
        }
    }
}

extern "C" void kernel_launch(void* const* d_in, const int* in_sizes, int n_in,
                              void* d_out, int out_size, void* d_ws, size_t ws_size,
                              hipStream_t stream) {
    const float* x  = (const float*)d_in[0];
    const int*   ei = (const int*)d_in[1];
    const float* W1 = (const float*)d_in[2];
    const float* b1 = (const float*)d_in[3];
    const float* W2 = (const float*)d_in[4];
    const float* b2 = (const float*)d_in[5];
    const float* W3 = (const float*)d_in[6];
    const float* b3 = (const float*)d_in[7];
    float* out = (float*)d_out;

    char* ws = (char*)d_ws;
    size_t off = 0;
    float* A        = (float*)(ws + off); off += (size_t)BN * FD * 4;     // 20.48 MB
    float* Bb       = (float*)(ws + off); off += (size_t)BN * FD * 4;     // 20.48 MB
    int*   edge_col = (int*)(ws + off);   off += (size_t)TOTE * 4;        // 5.12 MB
    int*   row_start= (int*)(ws + off);   off += (size_t)(BN + 1) * 4;
    float* dinv     = (float*)(ws + off); off += (size_t)BN * 4;
    int*   bsum     = (int*)(ws + off);   off += (size_t)SCB * 4;
    // rank + cnt/start2 alias Bb (dead after k_fill; Bb first rewritten by agg1)
    int*   rank     = (int*)Bb;
    int*   cnt      = (int*)Bb + (size_t)TOTE;

    k_count_lds<<<NPA, 256, 0, stream>>>(ei, rank, cnt);
    k_scanA<<<SCB, 1024, 0, stream>>>(cnt, row_start, dinv, bsum);
    k_scanC_lin<<<SCB + LIN2B, 256, 0, stream>>>(bsum, cnt, row_start,
                                                 x, W1, b1, dinv, A);     // A = t1'
    k_fill<<<FILLB, 256, 0, stream>>>(ei, rank, cnt, edge_col);
    k_agg<<<AGGB, 256, 0, stream>>>(A, row_start, edge_col, dinv, Bb);   // B = h1
    k_linear<<<LIN2B, 256, 0, stream>>>(Bb, W2, b2, dinv, A);            // A = t2'
    k_agg<<<AGGB, 256, 0, stream>>>(A, row_start, edge_col, dinv, Bb);   // B = h2
    k_linear<<<LIN2B, 256, 0, stream>>>(Bb, W3, b3, dinv, A);            // A = t3'
    k_agg<<<AGGB, 256, 0, stream>>>(A, row_start, edge_col, dinv, out);  // out = h3
}